// Round 12
// baseline (176.650 us; speedup 1.0000x reference)
//
#include <hip/hip_runtime.h>

typedef _Float16 f16;
typedef __attribute__((ext_vector_type(8))) _Float16 f16x8;
typedef __attribute__((ext_vector_type(4))) _Float16 f16x4;
typedef __attribute__((ext_vector_type(2))) __fp16 fp16x2;
typedef __attribute__((ext_vector_type(4))) float f32x4;
typedef unsigned int u32;
typedef __attribute__((ext_vector_type(2))) unsigned int u32x2;
typedef __attribute__((ext_vector_type(4))) unsigned int u32x4;

#define S_LEN 2048
#define NB 8
#define NH 4
#define DM 128
#define DK 32

static __device__ __forceinline__ f32x4 mfma_16x16x32(f16x8 a, f16x8 b, f32x4 c) {
  return __builtin_amdgcn_mfma_f32_16x16x32_f16(a, b, c, 0, 0, 0);
}
static __device__ __forceinline__ float exp2f_fast(float x) {
  return __builtin_amdgcn_exp2f(x);
}

union H8 { f16x8 v; fp16x2 h[4]; };
union H4 { f16x4 v; fp16x2 h[2]; };

// ---------------------------------------------------------------------------
// Kernel 0a: pack bool mask (uint8) into bit-words. word w bit j = mask[32w+j].
// ---------------------------------------------------------------------------
__global__ __launch_bounds__(256) void pack_mask_kernel(
    const unsigned char* __restrict__ mask, u32* __restrict__ words)
{
  const int tid = blockIdx.x * 256 + threadIdx.x;
  u32x4 v = *(const u32x4*)(mask + (size_t)tid * 16);
  u32 bits = 0;
#pragma unroll
  for (int i = 0; i < 4; ++i) {
    u32 u = v[i];
#pragma unroll
    for (int k = 0; k < 4; ++k)
      bits |= (((u >> (8 * k)) & 0xffu) ? 1u : 0u) << (4 * i + k);
  }
  u32 other = __shfl_xor(bits, 1);
  if ((threadIdx.x & 1) == 0) words[tid >> 1] = bits | (other << 16);
}

// ---------------------------------------------------------------------------
// Kernel 0b: transpose all four weight matrices to f16: wt[m][j*128+k]=W[k][j]
// ---------------------------------------------------------------------------
__global__ __launch_bounds__(256) void wtrans_kernel(
    const float* __restrict__ wq, const float* __restrict__ wk,
    const float* __restrict__ wv, const float* __restrict__ wo,
    f16* __restrict__ wt)
{
  const float* W = (blockIdx.x == 0) ? wq : (blockIdx.x == 1) ? wk
                 : (blockIdx.x == 2) ? wv : wo;
  f16* dst = wt + (size_t)blockIdx.x * 16384;
  __shared__ f16 tile[128 * 130];
  const int t = threadIdx.x;
#pragma unroll
  for (int i = 0; i < 16; ++i) {
    int idx = (i * 256 + t) * 4;
    f32x4 w4 = *(const f32x4*)(W + idx);
    int k = idx >> 7, j = idx & 127;
    tile[(j    ) * 130 + k] = (f16)w4[0];
    tile[(j + 1) * 130 + k] = (f16)w4[1];
    tile[(j + 2) * 130 + k] = (f16)w4[2];
    tile[(j + 3) * 130 + k] = (f16)w4[3];
  }
  __syncthreads();
#pragma unroll
  for (int i = 0; i < 8; ++i) {
    int lin = (i * 256 + t) * 8;
    int j = lin >> 7, k = lin & 127;
    f16x8 v;
#pragma unroll
    for (int r = 0; r < 8; ++r) v[r] = tile[j * 130 + k + r];
    *(f16x8*)(dst + lin) = v;
  }
}

// ---------------------------------------------------------------------------
// Kernel 1: MFMA q/k/v projections, W^T loaded directly from L2 (no staging).
// 4 waves x 16 rows. Depth-1 register prefetch over the 4 k-chunks.
// ---------------------------------------------------------------------------
__global__ __launch_bounds__(256, 2) void proj_kernel(
    const float* __restrict__ Qx, const float* __restrict__ Kx, const float* __restrict__ Vx,
    const f16* __restrict__ wt,
    const float* __restrict__ bq, const float* __restrict__ bk, const float* __restrict__ bv,
    f16* __restrict__ qh, f16* __restrict__ kh, f16* __restrict__ vt)
{
  const int mode = blockIdx.y;
  const float* X = (mode == 0) ? Qx : (mode == 1) ? Kx : Vx;
  const f16* wm = wt + (size_t)mode * 16384;
  const float* Bp = (mode == 0) ? bq : (mode == 1) ? bk : bv;

  const int wave = threadIdx.x >> 6, lane = threadIdx.x & 63;
  const int ln = lane & 15, hi = lane >> 4;
  const int rows0 = blockIdx.x * 64 + wave * 16;
  const int b = rows0 >> 11;
  const int s0 = rows0 & (S_LEN - 1);

  const float* xp = X + (size_t)(rows0 + ln) * DM + hi * 8;
  H8 hx[4];
#pragma unroll
  for (int kc = 0; kc < 4; ++kc) {
    f32x4 x0 = *(const f32x4*)(xp + kc * 32);
    f32x4 x1 = *(const f32x4*)(xp + kc * 32 + 4);
    hx[kc].h[0] = __builtin_amdgcn_cvt_pkrtz(x0[0], x0[1]);
    hx[kc].h[1] = __builtin_amdgcn_cvt_pkrtz(x0[2], x0[3]);
    hx[kc].h[2] = __builtin_amdgcn_cvt_pkrtz(x1[0], x1[1]);
    hx[kc].h[3] = __builtin_amdgcn_cvt_pkrtz(x1[2], x1[3]);
  }

  f32x4 acc[8];
#pragma unroll
  for (int jg = 0; jg < 8; ++jg) acc[jg] = (f32x4){0.f, 0.f, 0.f, 0.f};

  const f16* wp = wm + ln * 128 + hi * 8;
  f16x8 wf[8];
#pragma unroll
  for (int jg = 0; jg < 8; ++jg) wf[jg] = *(const f16x8*)(wp + jg * 2048);
#pragma unroll
  for (int kc = 0; kc < 4; ++kc) {
    f16x8 nwf[8];
    if (kc < 3) {
#pragma unroll
      for (int jg = 0; jg < 8; ++jg)
        nwf[jg] = *(const f16x8*)(wp + jg * 2048 + (kc + 1) * 32);
    }
    if (mode < 2) {
#pragma unroll
      for (int jg = 0; jg < 8; ++jg) acc[jg] = mfma_16x16x32(wf[jg], hx[kc].v, acc[jg]);
    } else {
#pragma unroll
      for (int jg = 0; jg < 8; ++jg) acc[jg] = mfma_16x16x32(hx[kc].v, wf[jg], acc[jg]);
    }
#pragma unroll
    for (int jg = 0; jg < 8; ++jg) wf[jg] = nwf[jg];
  }

  if (mode < 2) {
    const float sc = (mode == 0) ? 0.25503531f : 1.0f;  // log2e/sqrt(32)
    f16* outp = (mode == 0) ? qh : kh;
    const int s = s0 + ln;
#pragma unroll
    for (int jg = 0; jg < 8; ++jg) {
      int j0 = jg * 16 + hi * 4;
      f32x4 bb = *(const f32x4*)(Bp + j0);
      int h = jg >> 1;
      int dd0 = (jg & 1) * 16 + hi * 4;
      f16x4 e;
#pragma unroll
      for (int r = 0; r < 4; ++r) e[r] = (f16)((acc[jg][r] + bb[r]) * sc);
      *(f16x4*)(outp + ((size_t)(b * NH + h) * S_LEN + s) * DK + dd0) = e;
    }
  } else {
    const int t4 = s0 >> 5;
    const int halfq = (s0 >> 4) & 1;
#pragma unroll
    for (int jt = 0; jt < 8; ++jt) {
      int h = jt >> 1;
      int dv = (jt & 1) * 16 + ln;
      float bb = Bp[jt * 16 + ln];
      H4 u;
      u.h[0] = __builtin_amdgcn_cvt_pkrtz(acc[jt][0] + bb, acc[jt][1] + bb);
      u.h[1] = __builtin_amdgcn_cvt_pkrtz(acc[jt][2] + bb, acc[jt][3] + bb);
      f16* dst = vt + (size_t)(b * NH + h) * DK * S_LEN + t4 * 1024 + dv * 32 + hi * 8 + halfq * 4;
      *(f16x4*)dst = u.v;
    }
  }
}

// ---------------------------------------------------------------------------
// Kernel 2: attention. Block = 4 waves = 1 qtile (16 rows) x 4 kv-quarters
// (512 kv each). Grid = 4096 -> 4 scheduler generations at 4 blocks/CU:
// successive generations' pass-1 (exp/MFMA, storeless) backfills under
// resident blocks' pass-2 (write-bound), with a smaller cold head and drain
// tail than the 2-generation variant. XCD swizzle: 512 blocks (4 bh) per XCD.
// ---------------------------------------------------------------------------
__global__ __launch_bounds__(256, 4) void attn_kernel(
    const f16* __restrict__ qh, const f16* __restrict__ kh, const f16* __restrict__ vt,
    const u32* __restrict__ words,
    float* __restrict__ attn, float* __restrict__ ctx)
{
  const int lg = (blockIdx.x & 7) * 512 + (blockIdx.x >> 3);  // bijective, 4096
  const int bh = lg >> 7;               // 128 blocks per bh
  const int qp = lg & 127;              // 16-row tile index
  const int wave = threadIdx.x >> 6;    // kv quarter
  const int lane = threadIdx.x & 63;
  const int ln = lane & 15, hi = lane >> 4;
  const int b = bh >> 2, h = bh & 3;
  const int base = qp * 16;
  const int rA = base + ln;
  const int kv0 = wave * (S_LEN / 4);   // 512 kv per wave

  __shared__ f32x4 pt[4][16][16];       // per-wave transpose buf (4 KB each)
  __shared__ float sums[4][16];         // [quarter][ln]

  const f16* kbase = kh + (size_t)bh * S_LEN * DK;
  const f16* vbase = vt + (size_t)bh * DK * S_LEN;
  const u32* wrA = words + ((size_t)b * S_LEN + rA) * (S_LEN / 32);

  const f16x8 qA = *(const f16x8*)(qh + ((size_t)bh * S_LEN + rA) * DK + hi * 8);
  const f32x4 zero = {0.f, 0.f, 0.f, 0.f};

  // ---- pass 1: partial row sums, 64 kv/iter, depth-1 K+mask prefetch ----
  float smA = 0.f;
  {
    const f16* kp = kbase + (size_t)(kv0 + ln) * DK + hi * 8;
    const u32* mpA = wrA + (kv0 >> 5);
    f16x8 k0 = *(const f16x8*)(kp);
    f16x8 k1 = *(const f16x8*)(kp + 512);
    f16x8 k2 = *(const f16x8*)(kp + 1024);
    f16x8 k3 = *(const f16x8*)(kp + 1536);
    u32x2 mA = *(const u32x2*)mpA;
    for (int it = 0; it < 8; ++it) {
      f16x8 n0, n1, n2, n3;
      u32x2 nA;
      if (it < 7) {
        n0 = *(const f16x8*)(kp + 2048);
        n1 = *(const f16x8*)(kp + 2560);
        n2 = *(const f16x8*)(kp + 3072);
        n3 = *(const f16x8*)(kp + 3584);
        nA = *(const u32x2*)(mpA + 2);
      }
      f32x4 sA0 = mfma_16x16x32(k0, qA, zero);
      f32x4 sA1 = mfma_16x16x32(k1, qA, zero);
      f32x4 sA2 = mfma_16x16x32(k2, qA, zero);
      f32x4 sA3 = mfma_16x16x32(k3, qA, zero);
      if (__any((mA[0] | mA[1]) != 0u)) {
#pragma unroll
        for (int r = 0; r < 4; ++r) {
          float a0 = ((mA[0] >> (4 * hi + r)) & 1) ? 0.f : exp2f_fast(sA0[r]);
          float a1 = ((mA[0] >> (16 + 4 * hi + r)) & 1) ? 0.f : exp2f_fast(sA1[r]);
          float a2 = ((mA[1] >> (4 * hi + r)) & 1) ? 0.f : exp2f_fast(sA2[r]);
          float a3 = ((mA[1] >> (16 + 4 * hi + r)) & 1) ? 0.f : exp2f_fast(sA3[r]);
          smA += (a0 + a1) + (a2 + a3);
        }
      } else {
#pragma unroll
        for (int r = 0; r < 4; ++r) {
          smA += (exp2f_fast(sA0[r]) + exp2f_fast(sA1[r]))
               + (exp2f_fast(sA2[r]) + exp2f_fast(sA3[r]));
        }
      }
      k0 = n0; k1 = n1; k2 = n2; k3 = n3;
      mA = nA;
      kp += 2048; mpA += 2;
    }
  }
  smA += __shfl_xor(smA, 16);
  smA += __shfl_xor(smA, 32);
  if (lane < 16) sums[wave][ln] = smA;
  __syncthreads();
  const float linvA = -__builtin_amdgcn_logf(
      (sums[0][ln] + sums[1][ln]) + (sums[2][ln] + sums[3][ln]));

  // ---- pass 2: 64 kv/iter; stage->PV->transpose-store ----
  f32x4 cA0 = zero, cA1 = zero;
  {
    const f16* kp = kbase + (size_t)(kv0 + ln) * DK + hi * 8;
    const f16* vp = vbase + (size_t)(kv0 >> 5) * 1024 + ln * 32 + hi * 8;
    const u32* mpA = wrA + (kv0 >> 5);
    float* dstA = attn + ((size_t)bh * S_LEN + base) * S_LEN + kv0;
    f16x8 k0 = *(const f16x8*)(kp);
    f16x8 k1 = *(const f16x8*)(kp + 512);
    f16x8 k2 = *(const f16x8*)(kp + 1024);
    f16x8 k3 = *(const f16x8*)(kp + 1536);
    for (int it = 0; it < 8; ++it) {
      f16x8 v0 = *(const f16x8*)(vp);
      f16x8 v1 = *(const f16x8*)(vp + 512);
      f16x8 v2 = *(const f16x8*)(vp + 1024);
      f16x8 v3 = *(const f16x8*)(vp + 1536);
      f16x8 n0, n1, n2, n3;
      if (it < 7) {
        n0 = *(const f16x8*)(kp + 2048);
        n1 = *(const f16x8*)(kp + 2560);
        n2 = *(const f16x8*)(kp + 3072);
        n3 = *(const f16x8*)(kp + 3584);
      }
      u32x2 mA = *(const u32x2*)mpA;

      f32x4 s0 = mfma_16x16x32(k0, qA, zero);
      f32x4 s1 = mfma_16x16x32(k1, qA, zero);
      f32x4 s2 = mfma_16x16x32(k2, qA, zero);
      f32x4 s3 = mfma_16x16x32(k3, qA, zero);
      f32x4 p0, p1, p2, p3;
      if (__any((mA[0] | mA[1]) != 0u)) {
#pragma unroll
        for (int r = 0; r < 4; ++r) {
          p0[r] = ((mA[0] >> (4 * hi + r)) & 1) ? 0.f : exp2f_fast(s0[r] + linvA);
          p1[r] = ((mA[0] >> (16 + 4 * hi + r)) & 1) ? 0.f : exp2f_fast(s1[r] + linvA);
          p2[r] = ((mA[1] >> (4 * hi + r)) & 1) ? 0.f : exp2f_fast(s2[r] + linvA);
          p3[r] = ((mA[1] >> (16 + 4 * hi + r)) & 1) ? 0.f : exp2f_fast(s3[r] + linvA);
        }
      } else {
#pragma unroll
        for (int r = 0; r < 4; ++r) {
          p0[r] = exp2f_fast(s0[r] + linvA);
          p1[r] = exp2f_fast(s1[r] + linvA);
          p2[r] = exp2f_fast(s2[r] + linvA);
          p3[r] = exp2f_fast(s3[r] + linvA);
        }
      }
      pt[wave][ln][(0 + hi) ^ (ln & 7)] = p0;
      pt[wave][ln][(4 + hi) ^ (ln & 7)] = p1;
      pt[wave][ln][(8 + hi) ^ (ln & 7)] = p2;
      pt[wave][ln][(12 + hi) ^ (ln & 7)] = p3;
      H8 ua, ub;
      ua.h[0] = __builtin_amdgcn_cvt_pkrtz(p0[0], p0[1]);
      ua.h[1] = __builtin_amdgcn_cvt_pkrtz(p0[2], p0[3]);
      ua.h[2] = __builtin_amdgcn_cvt_pkrtz(p1[0], p1[1]);
      ua.h[3] = __builtin_amdgcn_cvt_pkrtz(p1[2], p1[3]);
      ub.h[0] = __builtin_amdgcn_cvt_pkrtz(p2[0], p2[1]);
      ub.h[1] = __builtin_amdgcn_cvt_pkrtz(p2[2], p2[3]);
      ub.h[2] = __builtin_amdgcn_cvt_pkrtz(p3[0], p3[1]);
      ub.h[3] = __builtin_amdgcn_cvt_pkrtz(p3[2], p3[3]);
      cA0 = mfma_16x16x32(v0, ua.v, cA0);
      cA1 = mfma_16x16x32(v1, ua.v, cA1);
      cA0 = mfma_16x16x32(v2, ub.v, cA0);
      cA1 = mfma_16x16x32(v3, ub.v, cA1);
#pragma unroll
      for (int s4 = 0; s4 < 4; ++s4) {
        int row = s4 * 4 + hi;
        f32x4 val = pt[wave][row][ln ^ (row & 7)];
        __builtin_nontemporal_store(val, (f32x4*)(dstA + (size_t)row * S_LEN + ln * 4));
      }
      k0 = n0; k1 = n1; k2 = n2; k3 = n3;
      kp += 2048; vp += 2048; mpA += 2;
      dstA += 64;
    }
  }

  // ---- combine 4 kv-quarter partial PVs (waves 1..3 overlay their pt) ----
  if (wave != 0) {
    float* cb = (float*)&pt[wave][0][0];  // 2 KB: [16 rows][32 dv]
#pragma unroll
    for (int r = 0; r < 4; ++r) {
      cb[ln * 32 + hi * 4 + r] = cA0[r];
      cb[ln * 32 + 16 + hi * 4 + r] = cA1[r];
    }
  }
  __syncthreads();
  if (wave == 0) {
#pragma unroll
    for (int w = 1; w < 4; ++w) {
      const float* cb = (const float*)&pt[w][0][0];
#pragma unroll
      for (int r = 0; r < 4; ++r) {
        cA0[r] += cb[ln * 32 + hi * 4 + r];
        cA1[r] += cb[ln * 32 + 16 + hi * 4 + r];
      }
    }
    float* crowA = ctx + ((size_t)b * S_LEN + rA) * DM + h * DK;
    *(f32x4*)(crowA + hi * 4) = cA0;
    *(f32x4*)(crowA + 16 + hi * 4) = cA1;
  }
}

// ---------------------------------------------------------------------------
// Kernel 3: out = LayerNorm(ctx @ wo + bo + residual(Q)). W^T direct from L2,
// LN fully in-register. 4 waves x 16 rows.
// ---------------------------------------------------------------------------
__global__ __launch_bounds__(256, 2) void out_ln_kernel(
    const float* __restrict__ ctx, const float* __restrict__ Qin,
    const f16* __restrict__ wt,
    const float* __restrict__ bo,
    const float* __restrict__ gamma, const float* __restrict__ beta,
    float* __restrict__ out)
{
  const f16* wm = wt + (size_t)3 * 16384;
  const int wave = threadIdx.x >> 6, lane = threadIdx.x & 63;
  const int ln = lane & 15, hi = lane >> 4;
  const int srow = blockIdx.x * 64 + wave * 16 + ln;

  const float* xp = ctx + (size_t)srow * DM + hi * 8;
  H8 hx[4];
#pragma unroll
  for (int kc = 0; kc < 4; ++kc) {
    f32x4 x0 = *(const f32x4*)(xp + kc * 32);
    f32x4 x1 = *(const f32x4*)(xp + kc * 32 + 4);
    hx[kc].h[0] = __builtin_amdgcn_cvt_pkrtz(x0[0], x0[1]);
    hx[kc].h[1] = __builtin_amdgcn_cvt_pkrtz(x0[2], x0[3]);
    hx[kc].h[2] = __builtin_amdgcn_cvt_pkrtz(x1[0], x1[1]);
    hx[kc].h[3] = __builtin_amdgcn_cvt_pkrtz(x1[2], x1[3]);
  }

  f32x4 acc[8];
#pragma unroll
  for (int jg = 0; jg < 8; ++jg) acc[jg] = (f32x4){0.f, 0.f, 0.f, 0.f};

  const f16* wp = wm + ln * 128 + hi * 8;
  f16x8 wf[8];
#pragma unroll
  for (int jg = 0; jg < 8; ++jg) wf[jg] = *(const f16x8*)(wp + jg * 2048);
#pragma unroll
  for (int kc = 0; kc < 4; ++kc) {
    f16x8 nwf[8];
    if (kc < 3) {
#pragma unroll
      for (int jg = 0; jg < 8; ++jg)
        nwf[jg] = *(const f16x8*)(wp + jg * 2048 + (kc + 1) * 32);
    }
#pragma unroll
    for (int jg = 0; jg < 8; ++jg) acc[jg] = mfma_16x16x32(wf[jg], hx[kc].v, acc[jg]);
#pragma unroll
    for (int jg = 0; jg < 8; ++jg) wf[jg] = nwf[jg];
  }

  float sm = 0.f, sq = 0.f;
#pragma unroll
  for (int jg = 0; jg < 8; ++jg) {
    int j0 = jg * 16 + hi * 4;
    f32x4 bb = *(const f32x4*)(bo + j0);
    f32x4 qq = *(const f32x4*)(Qin + (size_t)srow * DM + j0);
#pragma unroll
    for (int r = 0; r < 4; ++r) {
      float y = acc[jg][r] + bb[r] + qq[r];
      acc[jg][r] = y;
      sm += y; sq += y * y;
    }
  }
  sm += __shfl_xor(sm, 16); sm += __shfl_xor(sm, 32);
  sq += __shfl_xor(sq, 16); sq += __shfl_xor(sq, 32);
  const float mu = sm * (1.f / 128.f);
  const float var = sq * (1.f / 128.f) - mu * mu;
  const float rstd = rsqrtf(var + 1e-5f);
#pragma unroll
  for (int jg = 0; jg < 8; ++jg) {
    int j0 = jg * 16 + hi * 4;
    f32x4 g = *(const f32x4*)(gamma + j0);
    f32x4 be = *(const f32x4*)(beta + j0);
    f32x4 o;
#pragma unroll
    for (int r = 0; r < 4; ++r) o[r] = (acc[jg][r] - mu) * rstd * g[r] + be[r];
    *(f32x4*)(out + (size_t)srow * DM + j0) = o;
  }
}

// ---------------------------------------------------------------------------
extern "C" void kernel_launch(void* const* d_in, const int* in_sizes, int n_in,
                              void* d_out, int out_size, void* d_ws, size_t ws_size,
                              hipStream_t stream) {
  const float* Q    = (const float*)d_in[0];
  const float* K    = (const float*)d_in[1];
  const float* V    = (const float*)d_in[2];
  const unsigned char* mask = (const unsigned char*)d_in[3];
  const float* wq   = (const float*)d_in[4];
  const float* bq   = (const float*)d_in[5];
  const float* wk   = (const float*)d_in[6];
  const float* bk   = (const float*)d_in[7];
  const float* wv   = (const float*)d_in[8];
  const float* bv   = (const float*)d_in[9];
  const float* wo   = (const float*)d_in[10];
  const float* bo   = (const float*)d_in[11];
  const float* gamma= (const float*)d_in[12];
  const float* beta = (const float*)d_in[13];

  const size_t HEAD_ELEMS = (size_t)NB * NH * S_LEN * DK;  // 2,097,152

  f16* qh = (f16*)d_ws;
  f16* kh = qh + HEAD_ELEMS;
  f16* vt = kh + HEAD_ELEMS;
  float* ctx = (float*)(vt + HEAD_ELEMS);                  // 8 MB fp32
  u32* words = (u32*)(ctx + (size_t)NB * S_LEN * DM);      // 4 MB packed mask
  f16* wt = (f16*)(words + (size_t)NB * S_LEN * (S_LEN / 32));  // 128 KB W^T f16

  float* out  = (float*)d_out;                             // [8,2048,128]
  float* attn = out + (size_t)NB * S_LEN * DM;             // [8,4,2048,2048]

  pack_mask_kernel<<<8192, 256, 0, stream>>>(mask, words);
  wtrans_kernel<<<4, 256, 0, stream>>>(wq, wk, wv, wo, wt);
  proj_kernel<<<dim3(256, 3), 256, 0, stream>>>(Q, K, V, wt, bq, bk, bv, qh, kh, vt);
  attn_kernel<<<4096, 256, 0, stream>>>(qh, kh, vt, words, attn, ctx);
  out_ln_kernel<<<256, 256, 0, stream>>>(ctx, Q, wt, bo, gamma, beta, out);
}

// Round 13
// 160.675 us; speedup vs baseline: 1.0994x; 1.0994x over previous
//
#include <hip/hip_runtime.h>

typedef _Float16 f16;
typedef __attribute__((ext_vector_type(8))) _Float16 f16x8;
typedef __attribute__((ext_vector_type(4))) _Float16 f16x4;
typedef __attribute__((ext_vector_type(2))) __fp16 fp16x2;
typedef __attribute__((ext_vector_type(4))) float f32x4;
typedef unsigned int u32;
typedef __attribute__((ext_vector_type(2))) unsigned int u32x2;
typedef __attribute__((ext_vector_type(4))) unsigned int u32x4;

#define S_LEN 2048
#define NB 8
#define NH 4
#define DM 128
#define DK 32

static __device__ __forceinline__ f32x4 mfma_16x16x32(f16x8 a, f16x8 b, f32x4 c) {
  return __builtin_amdgcn_mfma_f32_16x16x32_f16(a, b, c, 0, 0, 0);
}
static __device__ __forceinline__ float exp2f_fast(float x) {
  return __builtin_amdgcn_exp2f(x);
}

union H8 { f16x8 v; fp16x2 h[4]; };
union H4 { f16x4 v; fp16x2 h[2]; };

// ---------------------------------------------------------------------------
// Kernel 0: transpose all four weight matrices to f16: wt[m][j*128+k]=W[k][j]
// ---------------------------------------------------------------------------
__global__ __launch_bounds__(256) void wtrans_kernel(
    const float* __restrict__ wq, const float* __restrict__ wk,
    const float* __restrict__ wv, const float* __restrict__ wo,
    f16* __restrict__ wt)
{
  const float* W = (blockIdx.x == 0) ? wq : (blockIdx.x == 1) ? wk
                 : (blockIdx.x == 2) ? wv : wo;
  f16* dst = wt + (size_t)blockIdx.x * 16384;
  __shared__ f16 tile[128 * 130];
  const int t = threadIdx.x;
#pragma unroll
  for (int i = 0; i < 16; ++i) {
    int idx = (i * 256 + t) * 4;
    f32x4 w4 = *(const f32x4*)(W + idx);
    int k = idx >> 7, j = idx & 127;
    tile[(j    ) * 130 + k] = (f16)w4[0];
    tile[(j + 1) * 130 + k] = (f16)w4[1];
    tile[(j + 2) * 130 + k] = (f16)w4[2];
    tile[(j + 3) * 130 + k] = (f16)w4[3];
  }
  __syncthreads();
#pragma unroll
  for (int i = 0; i < 8; ++i) {
    int lin = (i * 256 + t) * 8;
    int j = lin >> 7, k = lin & 127;
    f16x8 v;
#pragma unroll
    for (int r = 0; r < 8; ++r) v[r] = tile[j * 130 + k + r];
    *(f16x8*)(dst + lin) = v;
  }
}

// ---------------------------------------------------------------------------
// Kernel 1: fused proj (blocks 0..767) + mask pack (blocks 768..2815).
// proj: MFMA q/k/v projections, W^T from L2, 4 waves x 16 rows.
// pack: thread handles 64 contiguous mask bytes -> u32x2 store (no shuffles).
// ---------------------------------------------------------------------------
__global__ __launch_bounds__(256, 2) void proj_pack_kernel(
    const float* __restrict__ Qx, const float* __restrict__ Kx, const float* __restrict__ Vx,
    const f16* __restrict__ wt,
    const float* __restrict__ bq, const float* __restrict__ bk, const float* __restrict__ bv,
    f16* __restrict__ qh, f16* __restrict__ kh, f16* __restrict__ vt,
    const unsigned char* __restrict__ mask, u32* __restrict__ words)
{
  const int bx = blockIdx.x;
  if (bx >= 768) {
    // ---- pack: 2048 blocks x 256 threads x 64 B ----
    const size_t tid = (size_t)(bx - 768) * 256 + threadIdx.x;
    const unsigned char* src = mask + tid * 64;
    u32 w0 = 0, w1 = 0;
#pragma unroll
    for (int wi = 0; wi < 2; ++wi) {
      u32x4 a = *(const u32x4*)(src + wi * 32);
      u32x4 c = *(const u32x4*)(src + wi * 32 + 16);
      u32 bits = 0;
#pragma unroll
      for (int i = 0; i < 4; ++i) {
        u32 ua = a[i], uc = c[i];
#pragma unroll
        for (int k = 0; k < 4; ++k) {
          bits |= (((ua >> (8 * k)) & 0xffu) ? 1u : 0u) << (4 * i + k);
          bits |= (((uc >> (8 * k)) & 0xffu) ? 1u : 0u) << (16 + 4 * i + k);
        }
      }
      if (wi == 0) w0 = bits; else w1 = bits;
    }
    u32x2 o; o[0] = w0; o[1] = w1;
    *(u32x2*)(words + tid * 2) = o;
    return;
  }

  // ---- proj ----
  const int mode = bx >> 8;
  const int bxx = bx & 255;
  const float* X = (mode == 0) ? Qx : (mode == 1) ? Kx : Vx;
  const f16* wm = wt + (size_t)mode * 16384;
  const float* Bp = (mode == 0) ? bq : (mode == 1) ? bk : bv;

  const int wave = threadIdx.x >> 6, lane = threadIdx.x & 63;
  const int ln = lane & 15, hi = lane >> 4;
  const int rows0 = bxx * 64 + wave * 16;
  const int b = rows0 >> 11;
  const int s0 = rows0 & (S_LEN - 1);

  const float* xp = X + (size_t)(rows0 + ln) * DM + hi * 8;
  H8 hx[4];
#pragma unroll
  for (int kc = 0; kc < 4; ++kc) {
    f32x4 x0 = *(const f32x4*)(xp + kc * 32);
    f32x4 x1 = *(const f32x4*)(xp + kc * 32 + 4);
    hx[kc].h[0] = __builtin_amdgcn_cvt_pkrtz(x0[0], x0[1]);
    hx[kc].h[1] = __builtin_amdgcn_cvt_pkrtz(x0[2], x0[3]);
    hx[kc].h[2] = __builtin_amdgcn_cvt_pkrtz(x1[0], x1[1]);
    hx[kc].h[3] = __builtin_amdgcn_cvt_pkrtz(x1[2], x1[3]);
  }

  f32x4 acc[8];
#pragma unroll
  for (int jg = 0; jg < 8; ++jg) acc[jg] = (f32x4){0.f, 0.f, 0.f, 0.f};

  const f16* wp = wm + ln * 128 + hi * 8;
  f16x8 wf[8];
#pragma unroll
  for (int jg = 0; jg < 8; ++jg) wf[jg] = *(const f16x8*)(wp + jg * 2048);
#pragma unroll
  for (int kc = 0; kc < 4; ++kc) {
    f16x8 nwf[8];
    if (kc < 3) {
#pragma unroll
      for (int jg = 0; jg < 8; ++jg)
        nwf[jg] = *(const f16x8*)(wp + jg * 2048 + (kc + 1) * 32);
    }
    if (mode < 2) {
#pragma unroll
      for (int jg = 0; jg < 8; ++jg) acc[jg] = mfma_16x16x32(wf[jg], hx[kc].v, acc[jg]);
    } else {
#pragma unroll
      for (int jg = 0; jg < 8; ++jg) acc[jg] = mfma_16x16x32(hx[kc].v, wf[jg], acc[jg]);
    }
#pragma unroll
    for (int jg = 0; jg < 8; ++jg) wf[jg] = nwf[jg];
  }

  if (mode < 2) {
    const float sc = (mode == 0) ? 0.25503531f : 1.0f;  // log2e/sqrt(32)
    f16* outp = (mode == 0) ? qh : kh;
    const int s = s0 + ln;
#pragma unroll
    for (int jg = 0; jg < 8; ++jg) {
      int j0 = jg * 16 + hi * 4;
      f32x4 bb = *(const f32x4*)(Bp + j0);
      int h = jg >> 1;
      int dd0 = (jg & 1) * 16 + hi * 4;
      f16x4 e;
#pragma unroll
      for (int r = 0; r < 4; ++r) e[r] = (f16)((acc[jg][r] + bb[r]) * sc);
      *(f16x4*)(outp + ((size_t)(b * NH + h) * S_LEN + s) * DK + dd0) = e;
    }
  } else {
    const int t4 = s0 >> 5;
    const int halfq = (s0 >> 4) & 1;
#pragma unroll
    for (int jt = 0; jt < 8; ++jt) {
      int h = jt >> 1;
      int dv = (jt & 1) * 16 + ln;
      float bb = Bp[jt * 16 + ln];
      H4 u;
      u.h[0] = __builtin_amdgcn_cvt_pkrtz(acc[jt][0] + bb, acc[jt][1] + bb);
      u.h[1] = __builtin_amdgcn_cvt_pkrtz(acc[jt][2] + bb, acc[jt][3] + bb);
      f16* dst = vt + (size_t)(b * NH + h) * DK * S_LEN + t4 * 1024 + dv * 32 + hi * 8 + halfq * 4;
      *(f16x4*)dst = u.v;
    }
  }
}

// ---------------------------------------------------------------------------
// Kernel 2: attention. Block = 8 waves (512 thr) = 1 qtile (32 rows: subtiles
// A,B) x 8 kv-eighths (256 kv each). Grid = 2048, 2 blocks/CU -> 4 scheduler
// generations; per-block K/V traffic identical to the 32-row/4-wave variant.
// Pass-1 head and drain tail halve vs 2 generations. XCD swizzle: 4 bh/XCD.
// ---------------------------------------------------------------------------
__global__ __launch_bounds__(512, 4) void attn_kernel(
    const f16* __restrict__ qh, const f16* __restrict__ kh, const f16* __restrict__ vt,
    const u32* __restrict__ words,
    float* __restrict__ attn, float* __restrict__ ctx)
{
  const int lg = (blockIdx.x & 7) * 256 + (blockIdx.x >> 3);  // bijective, 2048
  const int bh = lg >> 6;               // 64 blocks per bh
  const int qp = lg & 63;               // 32-row tile index
  const int wave = threadIdx.x >> 6;    // kv eighth (0..7)
  const int lane = threadIdx.x & 63;
  const int ln = lane & 15, hi = lane >> 4;
  const int b = bh >> 2, h = bh & 3;
  const int base = qp * 32;
  const int rA = base + ln;
  const int rB = rA + 16;
  const int kv0 = wave * (S_LEN / 8);   // 256 kv per wave

  __shared__ f32x4 pt[8][2][16][16];    // per wave: 2 subtile transpose bufs (64 KB)
  __shared__ float sums[8][2][16];      // [eighth][sub][ln]

  const f16* kbase = kh + (size_t)bh * S_LEN * DK;
  const f16* vbase = vt + (size_t)bh * DK * S_LEN;
  const u32* wrA = words + ((size_t)b * S_LEN + rA) * (S_LEN / 32);
  const u32* wrB = words + ((size_t)b * S_LEN + rB) * (S_LEN / 32);

  const f16x8 qA = *(const f16x8*)(qh + ((size_t)bh * S_LEN + rA) * DK + hi * 8);
  const f16x8 qB = *(const f16x8*)(qh + ((size_t)bh * S_LEN + rB) * DK + hi * 8);
  const f32x4 zero = {0.f, 0.f, 0.f, 0.f};

  // ---- pass 1: partial row sums, 64 kv/iter x 4, depth-1 K+mask prefetch ----
  float smA = 0.f, smB = 0.f;
  {
    const f16* kp = kbase + (size_t)(kv0 + ln) * DK + hi * 8;
    const u32* mpA = wrA + (kv0 >> 5);
    const u32* mpB = wrB + (kv0 >> 5);
    f16x8 k0 = *(const f16x8*)(kp);
    f16x8 k1 = *(const f16x8*)(kp + 512);
    f16x8 k2 = *(const f16x8*)(kp + 1024);
    f16x8 k3 = *(const f16x8*)(kp + 1536);
    u32x2 mA = *(const u32x2*)mpA;
    u32x2 mB = *(const u32x2*)mpB;
    for (int it = 0; it < 4; ++it) {
      f16x8 n0, n1, n2, n3;
      u32x2 nA, nB;
      if (it < 3) {
        n0 = *(const f16x8*)(kp + 2048);
        n1 = *(const f16x8*)(kp + 2560);
        n2 = *(const f16x8*)(kp + 3072);
        n3 = *(const f16x8*)(kp + 3584);
        nA = *(const u32x2*)(mpA + 2);
        nB = *(const u32x2*)(mpB + 2);
      }
      f32x4 sA0 = mfma_16x16x32(k0, qA, zero);
      f32x4 sA1 = mfma_16x16x32(k1, qA, zero);
      f32x4 sA2 = mfma_16x16x32(k2, qA, zero);
      f32x4 sA3 = mfma_16x16x32(k3, qA, zero);
      f32x4 sB0 = mfma_16x16x32(k0, qB, zero);
      f32x4 sB1 = mfma_16x16x32(k1, qB, zero);
      f32x4 sB2 = mfma_16x16x32(k2, qB, zero);
      f32x4 sB3 = mfma_16x16x32(k3, qB, zero);
      if (__any(((mA[0] | mA[1]) | (mB[0] | mB[1])) != 0u)) {
#pragma unroll
        for (int r = 0; r < 4; ++r) {
          float a0 = ((mA[0] >> (4 * hi + r)) & 1) ? 0.f : exp2f_fast(sA0[r]);
          float a1 = ((mA[0] >> (16 + 4 * hi + r)) & 1) ? 0.f : exp2f_fast(sA1[r]);
          float a2 = ((mA[1] >> (4 * hi + r)) & 1) ? 0.f : exp2f_fast(sA2[r]);
          float a3 = ((mA[1] >> (16 + 4 * hi + r)) & 1) ? 0.f : exp2f_fast(sA3[r]);
          smA += (a0 + a1) + (a2 + a3);
          float b0 = ((mB[0] >> (4 * hi + r)) & 1) ? 0.f : exp2f_fast(sB0[r]);
          float b1 = ((mB[0] >> (16 + 4 * hi + r)) & 1) ? 0.f : exp2f_fast(sB1[r]);
          float b2 = ((mB[1] >> (4 * hi + r)) & 1) ? 0.f : exp2f_fast(sB2[r]);
          float b3 = ((mB[1] >> (16 + 4 * hi + r)) & 1) ? 0.f : exp2f_fast(sB3[r]);
          smB += (b0 + b1) + (b2 + b3);
        }
      } else {
#pragma unroll
        for (int r = 0; r < 4; ++r) {
          smA += (exp2f_fast(sA0[r]) + exp2f_fast(sA1[r])) + (exp2f_fast(sA2[r]) + exp2f_fast(sA3[r]));
          smB += (exp2f_fast(sB0[r]) + exp2f_fast(sB1[r])) + (exp2f_fast(sB2[r]) + exp2f_fast(sB3[r]));
        }
      }
      k0 = n0; k1 = n1; k2 = n2; k3 = n3;
      mA = nA; mB = nB;
      kp += 2048; mpA += 2; mpB += 2;
    }
  }
  smA += __shfl_xor(smA, 16); smA += __shfl_xor(smA, 32);
  smB += __shfl_xor(smB, 16); smB += __shfl_xor(smB, 32);
  if (lane < 16) { sums[wave][0][ln] = smA; sums[wave][1][ln] = smB; }
  __syncthreads();
  const float linvA = -__builtin_amdgcn_logf(
      ((sums[0][0][ln] + sums[1][0][ln]) + (sums[2][0][ln] + sums[3][0][ln])) +
      ((sums[4][0][ln] + sums[5][0][ln]) + (sums[6][0][ln] + sums[7][0][ln])));
  const float linvB = -__builtin_amdgcn_logf(
      ((sums[0][1][ln] + sums[1][1][ln]) + (sums[2][1][ln] + sums[3][1][ln])) +
      ((sums[4][1][ln] + sums[5][1][ln]) + (sums[6][1][ln] + sums[7][1][ln])));

  // ---- pass 2: 64 kv/iter x 4; per-subtile stage->PV->transpose-store ----
  f32x4 cA0 = zero, cA1 = zero, cB0 = zero, cB1 = zero;
  {
    const f16* kp = kbase + (size_t)(kv0 + ln) * DK + hi * 8;
    const f16* vp = vbase + (size_t)(kv0 >> 5) * 1024 + ln * 32 + hi * 8;
    const u32* mpA = wrA + (kv0 >> 5);
    const u32* mpB = wrB + (kv0 >> 5);
    float* dstA = attn + ((size_t)bh * S_LEN + base) * S_LEN + kv0;
    float* dstB = dstA + (size_t)16 * S_LEN;
    f16x8 k0 = *(const f16x8*)(kp);
    f16x8 k1 = *(const f16x8*)(kp + 512);
    f16x8 k2 = *(const f16x8*)(kp + 1024);
    f16x8 k3 = *(const f16x8*)(kp + 1536);
    for (int it = 0; it < 4; ++it) {
      f16x8 v0 = *(const f16x8*)(vp);
      f16x8 v1 = *(const f16x8*)(vp + 512);
      f16x8 v2 = *(const f16x8*)(vp + 1024);
      f16x8 v3 = *(const f16x8*)(vp + 1536);
      f16x8 n0, n1, n2, n3;
      if (it < 3) {
        n0 = *(const f16x8*)(kp + 2048);
        n1 = *(const f16x8*)(kp + 2560);
        n2 = *(const f16x8*)(kp + 3072);
        n3 = *(const f16x8*)(kp + 3584);
      }
      u32x2 mA = *(const u32x2*)mpA;
      u32x2 mB = *(const u32x2*)mpB;

      // ---- subtile A ----
      {
        f32x4 s0 = mfma_16x16x32(k0, qA, zero);
        f32x4 s1 = mfma_16x16x32(k1, qA, zero);
        f32x4 s2 = mfma_16x16x32(k2, qA, zero);
        f32x4 s3 = mfma_16x16x32(k3, qA, zero);
        f32x4 p0, p1, p2, p3;
        if (__any((mA[0] | mA[1]) != 0u)) {
#pragma unroll
          for (int r = 0; r < 4; ++r) {
            p0[r] = ((mA[0] >> (4 * hi + r)) & 1) ? 0.f : exp2f_fast(s0[r] + linvA);
            p1[r] = ((mA[0] >> (16 + 4 * hi + r)) & 1) ? 0.f : exp2f_fast(s1[r] + linvA);
            p2[r] = ((mA[1] >> (4 * hi + r)) & 1) ? 0.f : exp2f_fast(s2[r] + linvA);
            p3[r] = ((mA[1] >> (16 + 4 * hi + r)) & 1) ? 0.f : exp2f_fast(s3[r] + linvA);
          }
        } else {
#pragma unroll
          for (int r = 0; r < 4; ++r) {
            p0[r] = exp2f_fast(s0[r] + linvA);
            p1[r] = exp2f_fast(s1[r] + linvA);
            p2[r] = exp2f_fast(s2[r] + linvA);
            p3[r] = exp2f_fast(s3[r] + linvA);
          }
        }
        pt[wave][0][ln][(0 + hi) ^ (ln & 7)] = p0;
        pt[wave][0][ln][(4 + hi) ^ (ln & 7)] = p1;
        pt[wave][0][ln][(8 + hi) ^ (ln & 7)] = p2;
        pt[wave][0][ln][(12 + hi) ^ (ln & 7)] = p3;
        H8 ua, ub;
        ua.h[0] = __builtin_amdgcn_cvt_pkrtz(p0[0], p0[1]);
        ua.h[1] = __builtin_amdgcn_cvt_pkrtz(p0[2], p0[3]);
        ua.h[2] = __builtin_amdgcn_cvt_pkrtz(p1[0], p1[1]);
        ua.h[3] = __builtin_amdgcn_cvt_pkrtz(p1[2], p1[3]);
        ub.h[0] = __builtin_amdgcn_cvt_pkrtz(p2[0], p2[1]);
        ub.h[1] = __builtin_amdgcn_cvt_pkrtz(p2[2], p2[3]);
        ub.h[2] = __builtin_amdgcn_cvt_pkrtz(p3[0], p3[1]);
        ub.h[3] = __builtin_amdgcn_cvt_pkrtz(p3[2], p3[3]);
        cA0 = mfma_16x16x32(v0, ua.v, cA0);
        cA1 = mfma_16x16x32(v1, ua.v, cA1);
        cA0 = mfma_16x16x32(v2, ub.v, cA0);
        cA1 = mfma_16x16x32(v3, ub.v, cA1);
#pragma unroll
        for (int s4 = 0; s4 < 4; ++s4) {
          int row = s4 * 4 + hi;
          f32x4 val = pt[wave][0][row][ln ^ (row & 7)];
          __builtin_nontemporal_store(val, (f32x4*)(dstA + (size_t)row * S_LEN + ln * 4));
        }
      }
      // ---- subtile B ----
      {
        f32x4 s0 = mfma_16x16x32(k0, qB, zero);
        f32x4 s1 = mfma_16x16x32(k1, qB, zero);
        f32x4 s2 = mfma_16x16x32(k2, qB, zero);
        f32x4 s3 = mfma_16x16x32(k3, qB, zero);
        f32x4 p0, p1, p2, p3;
        if (__any((mB[0] | mB[1]) != 0u)) {
#pragma unroll
          for (int r = 0; r < 4; ++r) {
            p0[r] = ((mB[0] >> (4 * hi + r)) & 1) ? 0.f : exp2f_fast(s0[r] + linvB);
            p1[r] = ((mB[0] >> (16 + 4 * hi + r)) & 1) ? 0.f : exp2f_fast(s1[r] + linvB);
            p2[r] = ((mB[1] >> (4 * hi + r)) & 1) ? 0.f : exp2f_fast(s2[r] + linvB);
            p3[r] = ((mB[1] >> (16 + 4 * hi + r)) & 1) ? 0.f : exp2f_fast(s3[r] + linvB);
          }
        } else {
#pragma unroll
          for (int r = 0; r < 4; ++r) {
            p0[r] = exp2f_fast(s0[r] + linvB);
            p1[r] = exp2f_fast(s1[r] + linvB);
            p2[r] = exp2f_fast(s2[r] + linvB);
            p3[r] = exp2f_fast(s3[r] + linvB);
          }
        }
        pt[wave][1][ln][(0 + hi) ^ (ln & 7)] = p0;
        pt[wave][1][ln][(4 + hi) ^ (ln & 7)] = p1;
        pt[wave][1][ln][(8 + hi) ^ (ln & 7)] = p2;
        pt[wave][1][ln][(12 + hi) ^ (ln & 7)] = p3;
        H8 ua, ub;
        ua.h[0] = __builtin_amdgcn_cvt_pkrtz(p0[0], p0[1]);
        ua.h[1] = __builtin_amdgcn_cvt_pkrtz(p0[2], p0[3]);
        ua.h[2] = __builtin_amdgcn_cvt_pkrtz(p1[0], p1[1]);
        ua.h[3] = __builtin_amdgcn_cvt_pkrtz(p1[2], p1[3]);
        ub.h[0] = __builtin_amdgcn_cvt_pkrtz(p2[0], p2[1]);
        ub.h[1] = __builtin_amdgcn_cvt_pkrtz(p2[2], p2[3]);
        ub.h[2] = __builtin_amdgcn_cvt_pkrtz(p3[0], p3[1]);
        ub.h[3] = __builtin_amdgcn_cvt_pkrtz(p3[2], p3[3]);
        cB0 = mfma_16x16x32(v0, ua.v, cB0);
        cB1 = mfma_16x16x32(v1, ua.v, cB1);
        cB0 = mfma_16x16x32(v2, ub.v, cB0);
        cB1 = mfma_16x16x32(v3, ub.v, cB1);
#pragma unroll
        for (int s4 = 0; s4 < 4; ++s4) {
          int row = s4 * 4 + hi;
          f32x4 val = pt[wave][1][row][ln ^ (row & 7)];
          __builtin_nontemporal_store(val, (f32x4*)(dstB + (size_t)row * S_LEN + ln * 4));
        }
      }
      k0 = n0; k1 = n1; k2 = n2; k3 = n3;
      kp += 2048; vp += 2048; mpA += 2; mpB += 2;
      dstA += 64; dstB += 64;
    }
  }

  // ---- combine 8 kv-eighth partial PVs (waves 1..7 overlay their pt) ----
  if (wave != 0) {
    float* cb = (float*)&pt[wave][0][0][0];  // 4 KB: [32 rows][32 dv]
#pragma unroll
    for (int r = 0; r < 4; ++r) {
      cb[ln * 32 + hi * 4 + r] = cA0[r];
      cb[ln * 32 + 16 + hi * 4 + r] = cA1[r];
      cb[(16 + ln) * 32 + hi * 4 + r] = cB0[r];
      cb[(16 + ln) * 32 + 16 + hi * 4 + r] = cB1[r];
    }
  }
  __syncthreads();
  if (wave == 0) {
#pragma unroll
    for (int w = 1; w < 8; ++w) {
      const float* cb = (const float*)&pt[w][0][0][0];
#pragma unroll
      for (int r = 0; r < 4; ++r) {
        cA0[r] += cb[ln * 32 + hi * 4 + r];
        cA1[r] += cb[ln * 32 + 16 + hi * 4 + r];
        cB0[r] += cb[(16 + ln) * 32 + hi * 4 + r];
        cB1[r] += cb[(16 + ln) * 32 + 16 + hi * 4 + r];
      }
    }
    float* crowA = ctx + ((size_t)b * S_LEN + rA) * DM + h * DK;
    float* crowB = ctx + ((size_t)b * S_LEN + rB) * DM + h * DK;
    *(f32x4*)(crowA + hi * 4) = cA0;
    *(f32x4*)(crowA + 16 + hi * 4) = cA1;
    *(f32x4*)(crowB + hi * 4) = cB0;
    *(f32x4*)(crowB + 16 + hi * 4) = cB1;
  }
}

// ---------------------------------------------------------------------------
// Kernel 3: out = LayerNorm(ctx @ wo + bo + residual(Q)). W^T direct from L2,
// LN fully in-register. 4 waves x 16 rows.
// ---------------------------------------------------------------------------
__global__ __launch_bounds__(256, 2) void out_ln_kernel(
    const float* __restrict__ ctx, const float* __restrict__ Qin,
    const f16* __restrict__ wt,
    const float* __restrict__ bo,
    const float* __restrict__ gamma, const float* __restrict__ beta,
    float* __restrict__ out)
{
  const f16* wm = wt + (size_t)3 * 16384;
  const int wave = threadIdx.x >> 6, lane = threadIdx.x & 63;
  const int ln = lane & 15, hi = lane >> 4;
  const int srow = blockIdx.x * 64 + wave * 16 + ln;

  const float* xp = ctx + (size_t)srow * DM + hi * 8;
  H8 hx[4];
#pragma unroll
  for (int kc = 0; kc < 4; ++kc) {
    f32x4 x0 = *(const f32x4*)(xp + kc * 32);
    f32x4 x1 = *(const f32x4*)(xp + kc * 32 + 4);
    hx[kc].h[0] = __builtin_amdgcn_cvt_pkrtz(x0[0], x0[1]);
    hx[kc].h[1] = __builtin_amdgcn_cvt_pkrtz(x0[2], x0[3]);
    hx[kc].h[2] = __builtin_amdgcn_cvt_pkrtz(x1[0], x1[1]);
    hx[kc].h[3] = __builtin_amdgcn_cvt_pkrtz(x1[2], x1[3]);
  }

  f32x4 acc[8];
#pragma unroll
  for (int jg = 0; jg < 8; ++jg) acc[jg] = (f32x4){0.f, 0.f, 0.f, 0.f};

  const f16* wp = wm + ln * 128 + hi * 8;
  f16x8 wf[8];
#pragma unroll
  for (int jg = 0; jg < 8; ++jg) wf[jg] = *(const f16x8*)(wp + jg * 2048);
#pragma unroll
  for (int kc = 0; kc < 4; ++kc) {
    f16x8 nwf[8];
    if (kc < 3) {
#pragma unroll
      for (int jg = 0; jg < 8; ++jg)
        nwf[jg] = *(const f16x8*)(wp + jg * 2048 + (kc + 1) * 32);
    }
#pragma unroll
    for (int jg = 0; jg < 8; ++jg) acc[jg] = mfma_16x16x32(wf[jg], hx[kc].v, acc[jg]);
#pragma unroll
    for (int jg = 0; jg < 8; ++jg) wf[jg] = nwf[jg];
  }

  float sm = 0.f, sq = 0.f;
#pragma unroll
  for (int jg = 0; jg < 8; ++jg) {
    int j0 = jg * 16 + hi * 4;
    f32x4 bb = *(const f32x4*)(bo + j0);
    f32x4 qq = *(const f32x4*)(Qin + (size_t)srow * DM + j0);
#pragma unroll
    for (int r = 0; r < 4; ++r) {
      float y = acc[jg][r] + bb[r] + qq[r];
      acc[jg][r] = y;
      sm += y; sq += y * y;
    }
  }
  sm += __shfl_xor(sm, 16); sm += __shfl_xor(sm, 32);
  sq += __shfl_xor(sq, 16); sq += __shfl_xor(sq, 32);
  const float mu = sm * (1.f / 128.f);
  const float var = sq * (1.f / 128.f) - mu * mu;
  const float rstd = rsqrtf(var + 1e-5f);
#pragma unroll
  for (int jg = 0; jg < 8; ++jg) {
    int j0 = jg * 16 + hi * 4;
    f32x4 g = *(const f32x4*)(gamma + j0);
    f32x4 be = *(const f32x4*)(beta + j0);
    f32x4 o;
#pragma unroll
    for (int r = 0; r < 4; ++r) o[r] = (acc[jg][r] - mu) * rstd * g[r] + be[r];
    *(f32x4*)(out + (size_t)srow * DM + j0) = o;
  }
}

// ---------------------------------------------------------------------------
extern "C" void kernel_launch(void* const* d_in, const int* in_sizes, int n_in,
                              void* d_out, int out_size, void* d_ws, size_t ws_size,
                              hipStream_t stream) {
  const float* Q    = (const float*)d_in[0];
  const float* K    = (const float*)d_in[1];
  const float* V    = (const float*)d_in[2];
  const unsigned char* mask = (const unsigned char*)d_in[3];
  const float* wq   = (const float*)d_in[4];
  const float* bq   = (const float*)d_in[5];
  const float* wk   = (const float*)d_in[6];
  const float* bk   = (const float*)d_in[7];
  const float* wv   = (const float*)d_in[8];
  const float* bv   = (const float*)d_in[9];
  const float* wo   = (const float*)d_in[10];
  const float* bo   = (const float*)d_in[11];
  const float* gamma= (const float*)d_in[12];
  const float* beta = (const float*)d_in[13];

  const size_t HEAD_ELEMS = (size_t)NB * NH * S_LEN * DK;  // 2,097,152

  f16* qh = (f16*)d_ws;
  f16* kh = qh + HEAD_ELEMS;
  f16* vt = kh + HEAD_ELEMS;
  float* ctx = (float*)(vt + HEAD_ELEMS);                  // 8 MB fp32
  u32* words = (u32*)(ctx + (size_t)NB * S_LEN * DM);      // 4 MB packed mask
  f16* wt = (f16*)(words + (size_t)NB * S_LEN * (S_LEN / 32));  // 128 KB W^T f16

  float* out  = (float*)d_out;                             // [8,2048,128]
  float* attn = out + (size_t)NB * S_LEN * DM;             // [8,4,2048,2048]

  wtrans_kernel<<<4, 256, 0, stream>>>(wq, wk, wv, wo, wt);
  proj_pack_kernel<<<2816, 256, 0, stream>>>(Q, K, V, wt, bq, bk, bv, qh, kh, vt, mask, words);
  attn_kernel<<<2048, 512, 0, stream>>>(qh, kh, vt, words, attn, ctx);
  out_ln_kernel<<<256, 256, 0, stream>>>(ctx, Q, wt, bo, gamma, beta, out);
}